// Round 1
// 194.924 us; speedup vs baseline: 1.0197x; 1.0197x over previous
//
#include <hip/hip_runtime.h>

// mp: [1, 21, 16, 256, 256] fp32
#define CC   21
#define DD   16
#define HH   256
#define WW   256
#define HWP  (HH * WW)      // 65536
#define DHW  (DD * HWP)     // 1048576

typedef float f4a __attribute__((ext_vector_type(4), aligned(16)));
__device__ __forceinline__ f4a f4add(f4a a, f4a b) { return a + b; }

// ---------------------------------------------------------------------------
// K1: D-blur (registers) + H-blur (LDS), NO W-blur, NO W-halo.
// Tile: one channel, full D=16, H=8 (stage 12 rows), W=32 (8 aligned quads).
// Stage: 192 tasks = 96 cols (12 py x 8 x4) x 2 d-splits; 12 vec4 loads each,
// sliding 5-tap D-sum, 8 plane-writes to A. Write banks: (16*plane + 4*py +
// 4*x4) mod 32 -> (py+x4) mod 8 hits each residue exactly 8x per wave ->
// conflict-free by construction (the old 9-col jjq layout was 7-9 imbalanced).
// H pass: 1024 tasks (4/thread), 5 aligned b128 reads each (rows y..y+4),
// aligned float4 store of the DH-sum to global. AROW=36 kept (144 B row,
// 16B-aligned, stride ≡4 mod 32 -> read phases cover all banks exactly once).
// ---------------------------------------------------------------------------
#define AROW 36
#define PYN  12
#define A_SZ (DD * PYN * AROW)   // 6912 floats = 27648 B -> 5 blocks/CU

__global__ __launch_bounds__(256, 5) void dh_blur_kernel(const float* __restrict__ mp,
                                                         float* __restrict__ out) {
    __shared__ float A[A_SZ];

    const int w0 = blockIdx.x * 32;
    const int h0 = blockIdx.y * 8;
    const int ch = blockIdx.z;
    const int tid = threadIdx.x;
    const float* __restrict__ src = mp + (size_t)ch * DHW;

    if (tid < 192) {
        const int s   = (tid >= 96) ? 1 : 0;   // output planes s*8 .. s*8+7
        const int col = tid - s * 96;
        const int py  = col >> 3;              // 0..11
        const int x4  = col & 7;               // quad 0..7 (no W halo!)
        const int h   = min(HH - 1, max(0, h0 + py - 2));
        const float* colp = src + (size_t)h * WW + w0 + x4 * 4;

        f4a l[12];
#pragma unroll
        for (int m = 0; m < 12; ++m) {
            int dz = s * 8 + m;                       // staged plane 0..19
            int d  = min(DD - 1, max(0, dz - 2));     // replicate clamp in D
            l[m] = *(const f4a*)(colp + (size_t)d * HWP);
        }
        // identical summation order to the verified kernel:
        f4a sum = f4add(f4add(f4add(l[0], l[1]), f4add(l[2], l[3])), l[4]);
#pragma unroll
        for (int i = 0; i < 8; ++i) {
            *(f4a*)(&A[((s * 8 + i) * PYN + py) * AROW + x4 * 4]) = sum;
            if (i < 7) sum = sum - l[i] + l[i + 5];
        }
    }
    __syncthreads();

    // H pass: t = dout*64 + y*8 + x4
#pragma unroll
    for (int it = 0; it < 4; ++it) {
        const int t    = tid + it * 256;
        const int x4   = t & 7;
        const int y    = (t >> 3) & 7;
        const int dout = t >> 6;

        const float* b = &A[(dout * PYN + y) * AROW + x4 * 4];
        f4a a = *(const f4a*)b;
#pragma unroll
        for (int k = 1; k < 5; ++k) a = f4add(a, *(const f4a*)(b + k * AROW));

        *(f4a*)(out + (size_t)ch * DHW + (size_t)dout * HWP
                + (h0 + y) * WW + w0 + x4 * 4) = a;
    }
}

// ---------------------------------------------------------------------------
// K2: W-blur + weighted-median, fused, in place on the DH-blurred buffer.
// Block = one (d,h) row, all 21 channels staged in LDS (21 x 264 floats =
// 22.2 KB -> 7 blocks/CU, 28 waves). Each row is read and overwritten only by
// its own block (W-blur needs nothing outside the row) -> in-place is safe.
// Thread = one w pixel: v[c] = 5-tap W sum from LDS (edge-replicated slots),
// then the exact median arithmetic of the verified kernel (tot ascending,
// inv = 1/tot, yn = v*inv, same conditions) -> bitwise-identical selection.
// ---------------------------------------------------------------------------
#define ROWP 264   // 2 pad + 2 lo-edge + 256 data + 2 hi-edge + 2 pad (16B-aligned quads at +4)

__global__ __launch_bounds__(256) void wmedian_kernel(float* __restrict__ y4) {
    __shared__ float R[CC * ROWP];

    const int h = blockIdx.x;
    const int d = blockIdx.y;
    const int tid = threadIdx.x;
    float* __restrict__ base = y4 + (size_t)d * HWP + (size_t)h * WW;

    // stage: 21 rows x 64 aligned float4 (1344 loads, 1 KB contiguous per wave)
    for (int idx = tid; idx < CC * 64; idx += 256) {
        const int c  = idx >> 6;
        const int w4 = idx & 63;
        *(f4a*)(&R[c * ROWP + 4 + w4 * 4]) = *(const f4a*)(base + (size_t)c * DHW + w4 * 4);
    }
    // replicate edges (loaded straight from global; no dependence on stage order)
    if (tid < CC) {
        const float v0 = base[(size_t)tid * DHW];
        const float vL = base[(size_t)tid * DHW + (WW - 1)];
        R[tid * ROWP + 2]   = v0;
        R[tid * ROWP + 3]   = v0;
        R[tid * ROWP + 260] = vL;
        R[tid * ROWP + 261] = vL;
    }
    __syncthreads();

    const int w = tid;   // 0..255
    float v[CC];
    float tot = 0.f;
#pragma unroll
    for (int c = 0; c < CC; ++c) {
        const float* r = &R[c * ROWP + 2 + w];   // r[0] = value at w-2
        v[c] = ((((r[0] + r[1]) + r[2]) + r[3]) + r[4]);   // same W order as before
        tot += v[c];
    }
    const float inv = 1.0f / tot;

    float s = 0.f, sv0 = 0.f, sv1 = 0.f;
    int m0 = 0, m1 = 0;
#pragma unroll
    for (int c = 0; c < CC; ++c) {
        const float yn = v[c] * inv;
        const float sn = s + yn;
        if (c == 0) { sv0 = yn; sv1 = yn; }                           // defaults
        if (v[c] > 0.f && sn < 0.5f) { m0 = c; sv0 = yn; }            // last qualifying
        if (m1 == 0 && c > 0 && sn > 0.5f) { m1 = c; sv1 = yn; }      // first qualifying
        s = sn;
    }

#pragma unroll
    for (int c = 0; c < CC; ++c) {
        base[(size_t)c * DHW + w] = (c == m0) ? sv0 : ((c == m1) ? sv1 : 0.f);
    }
}

extern "C" void kernel_launch(void* const* d_in, const int* in_sizes, int n_in,
                              void* d_out, int out_size, void* d_ws, size_t ws_size,
                              hipStream_t stream) {
    const float* mp = (const float*)d_in[0];
    float* out = (float*)d_out;

    dh_blur_kernel<<<dim3(WW / 32, HH / 8, CC), 256, 0, stream>>>(mp, out);   // 5376 blocks
    wmedian_kernel<<<dim3(HH, DD), 256, 0, stream>>>(out);                    // 4096 blocks
}